// Round 4
// baseline (262.498 us; speedup 1.0000x reference)
//
#include <hip/hip_runtime.h>
#include <hip/hip_bf16.h>
#include <math.h>

#define NN 2048
#define NEG_SLOPE 0.2f

typedef __attribute__((ext_vector_type(8))) short bf16x8;
typedef __attribute__((ext_vector_type(4))) float f32x4;

static __device__ inline short f2bf(float x) {
  union { float f; unsigned u; } v;
  v.f = x;
  unsigned r = v.u + 0x7fffu + ((v.u >> 16) & 1u);  // RNE
  return (short)(r >> 16);
}

// ---------------------------------------------------------------------------
// K1: agg[s,t] = sum_c conv_w[c]*attn[c,s,t] + conv_b ; store TRANSPOSED
//     aggT[t][s], plus atomic per-target column stats (sum/cnt of masked).
// Block: 1024 t (float4/lane) x 16 s. Grid (2,128).
// ---------------------------------------------------------------------------
__global__ __launch_bounds__(256) void k_agg(const float* __restrict__ attn,
                                             const float* __restrict__ conv_w,
                                             const float* __restrict__ conv_b,
                                             float* __restrict__ aggT,
                                             float* __restrict__ colsum,
                                             float* __restrict__ colcnt) {
  const int t = blockIdx.x * 1024 + threadIdx.x * 4;
  const int s0 = blockIdx.y * 16;
  float w[12];
#pragma unroll
  for (int c = 0; c < 12; ++c) w[c] = conv_w[c];
  const float cb = conv_b[0];
  f32x4 acc[16];
#pragma unroll
  for (int s = 0; s < 16; ++s) acc[s] = (f32x4){cb, cb, cb, cb};
  for (int c = 0; c < 12; ++c) {
    const float* base = attn + (size_t)c * NN * NN + (size_t)s0 * NN + t;
#pragma unroll
    for (int s = 0; s < 16; ++s) {
      f32x4 v = *(const f32x4*)(base + (size_t)s * NN);
      acc[s] += w[c] * v;
    }
  }
  // write aggT rows
#pragma unroll
  for (int j = 0; j < 4; ++j) {
    float* orow = aggT + (size_t)(t + j) * NN + s0;
#pragma unroll
    for (int s = 0; s < 16; ++s) orow[s] = acc[s][j];
  }
  // stats: per target t+j over these 16 sources
#pragma unroll
  for (int j = 0; j < 4; ++j) {
    float psum = 0.f;
    float pcnt = 0.f;
#pragma unroll
    for (int s = 0; s < 16; ++s) {
      float a = acc[s][j];
      bool m = (a > 0.f) && (s0 + s != t + j);
      psum += m ? a : 0.f;
      pcnt += m ? 1.f : 0.f;
    }
    atomicAdd(colsum + t + j, psum);
    atomicAdd(colcnt + t + j, pcnt);
  }
}

// ---------------------------------------------------------------------------
// Setup kernel (block ranges): xb (0-255), w1t (256-287), w2t (288-319),
// mean_attr (320-327), ce (328).
// ---------------------------------------------------------------------------
__global__ __launch_bounds__(256) void k_setup(
    const float* __restrict__ x, const float* __restrict__ W1,
    const float* __restrict__ W2, const float* __restrict__ ae1,
    const float* __restrict__ We1, const float* __restrict__ ae2,
    const float* __restrict__ We2, const float* __restrict__ colsum,
    const float* __restrict__ colcnt, __hip_bfloat16* __restrict__ xb,
    __hip_bfloat16* __restrict__ w1t, __hip_bfloat16* __restrict__ w2t,
    float* __restrict__ mean_attr, float* __restrict__ ce) {
  const int b = blockIdx.x;
  const int tid = threadIdx.x;
  if (b < 256) {
    const int i = (b * 256 + tid) * 4;
    float4 v = *(const float4*)(x + i);
    short4 o;
    o.x = f2bf(v.x); o.y = f2bf(v.y); o.z = f2bf(v.z); o.w = f2bf(v.w);
    *(short4*)((short*)xb + i) = o;
  } else if (b < 288) {
#pragma unroll
    for (int k = 0; k < 8; ++k) {
      int o = (b - 256) * 2048 + k * 256 + tid;
      int c = o >> 7, r = o & 127;
      ((short*)w1t)[o] = f2bf(W1[r * 512 + c]);
    }
  } else if (b < 320) {
#pragma unroll
    for (int k = 0; k < 8; ++k) {
      int o = (b - 288) * 2048 + k * 256 + tid;
      int c = o >> 9, r = o & 511;
      ((short*)w2t)[o] = f2bf(W2[r * 128 + c]);
    }
  } else if (b < 328) {
    int t = (b - 320) * 256 + tid;
    float c = colcnt[t];
    mean_attr[t] = colsum[t] / fmaxf(c, 1.f);
  } else {
    const int lane = tid & 63;
    const int wv = tid >> 6;
    float p = ae1[wv * 128 + lane] * We1[wv * 128 + lane] +
              ae1[wv * 128 + 64 + lane] * We1[wv * 128 + 64 + lane];
    for (int off = 32; off; off >>= 1) p += __shfl_down(p, off);
    if (lane == 0) ce[wv] = p;
    float q = ae2[lane] * We2[lane] + ae2[64 + lane] * We2[64 + lane];
    for (int off = 32; off; off >>= 1) q += __shfl_down(q, off);
    if (tid == 0) ce[4] = q;
  }
}

// ---------------------------------------------------------------------------
// MFMA GEMM, 1 wave/block: out tile 16 rows x 64 cols. Writes ONLY the
// swizzled bf16 layout hTsw[cb][s/8][16cr][8s] (cb = 16-col block), and fused
// s_src/s_dst partial dots via atomicAdd (buffers pre-zeroed).
// ---------------------------------------------------------------------------
template <int KSTEPS, int NH>
__global__ __launch_bounds__(64) void k_gemm_fused(
    const __hip_bfloat16* __restrict__ A, const __hip_bfloat16* __restrict__ BT,
    __hip_bfloat16* __restrict__ hTsw, const float* __restrict__ asrc,
    const float* __restrict__ adst, float* __restrict__ ssrc,
    float* __restrict__ sdst) {
  constexpr int K = KSTEPS * 32;
  const int m0 = blockIdx.x * 16;
  const int n0 = blockIdx.y * 64;
  const int lane = threadIdx.x;
  const int row = lane & 15;
  const int kg = lane >> 4;
  const __hip_bfloat16* arow = A + (size_t)(m0 + row) * K + kg * 8;
  f32x4 acc[4];
#pragma unroll
  for (int f = 0; f < 4; ++f) acc[f] = (f32x4){0.f, 0.f, 0.f, 0.f};
#pragma unroll
  for (int ks = 0; ks < KSTEPS; ++ks) {
    bf16x8 Af = *(const bf16x8*)(arow + ks * 32);
#pragma unroll
    for (int f = 0; f < 4; ++f) {
      bf16x8 Bf = *(const bf16x8*)(BT + (size_t)(n0 + f * 16 + row) * K +
                                   kg * 8 + ks * 32);
      acc[f] = __builtin_amdgcn_mfma_f32_16x16x32_bf16(Af, Bf, acc[f], 0, 0, 0);
    }
  }
  // fused s_src/s_dst partials
  const int h = (NH == 1) ? 0 : (n0 >> 7);
  float as[4], ad[4];
#pragma unroll
  for (int f = 0; f < 4; ++f) {
    int ch = (n0 + f * 16 + row) & 127;
    as[f] = asrc[h * 128 + ch];
    ad[f] = adst[h * 128 + ch];
  }
  float ps[4] = {0.f, 0.f, 0.f, 0.f}, pd[4] = {0.f, 0.f, 0.f, 0.f};
#pragma unroll
  for (int f = 0; f < 4; ++f)
#pragma unroll
    for (int r = 0; r < 4; ++r) {
      ps[r] += acc[f][r] * as[f];
      pd[r] += acc[f][r] * ad[f];
    }
#pragma unroll
  for (int m = 1; m < 16; m <<= 1) {
#pragma unroll
    for (int r = 0; r < 4; ++r) {
      ps[r] += __shfl_xor(ps[r], m);
      pd[r] += __shfl_xor(pd[r], m);
    }
  }
  if (row == 0) {
#pragma unroll
    for (int r = 0; r < 4; ++r) {
      int node = m0 + kg * 4 + r;
      atomicAdd(&ssrc[node * NH + h], ps[r]);
      atomicAdd(&sdst[node * NH + h], pd[r]);
    }
  }
  // swizzled bf16 write: elem addr = cb*NN*16 + sblk*128 + cr*8 + (s&7)
#pragma unroll
  for (int f = 0; f < 4; ++f) {
    const int cbi = blockIdx.y * 4 + f;
    short4 ct;
    ct.x = f2bf(acc[f][0]); ct.y = f2bf(acc[f][1]);
    ct.z = f2bf(acc[f][2]); ct.w = f2bf(acc[f][3]);
    size_t a4 = (size_t)cbi * (NN * 16) +
                (size_t)(((m0 >> 3) + (kg >> 1)) * 128 + row * 8 + (kg & 1) * 4);
    *(short4*)((short*)hTsw + a4) = ct;
  }
}

// ---------------------------------------------------------------------------
// Layer-1 fused attention: 4 waves = 4 heads sharing 16 target rows.
// B-frags from swizzled hTsw: one contiguous 1KB block per wave per load.
// ---------------------------------------------------------------------------
template <int SPLITS>
__global__ __launch_bounds__(256) void k_attn1(
    const float* __restrict__ aggT, const __hip_bfloat16* __restrict__ hTsw,
    const float* __restrict__ ssrc, const float* __restrict__ sdst,
    const float* __restrict__ mean_attr, const float* __restrict__ ce_all,
    float* __restrict__ num, float* __restrict__ dden) {
  constexpr int SLEN = NN / SPLITS;
  const int t0 = blockIdx.x * 16;
  const int split = blockIdx.y;
  const int sbeg = split * SLEN;

  __shared__ float ss_sh[4 * SLEN];
  for (int i = threadIdx.x; i < 4 * SLEN; i += 256) {
    int hh = i / SLEN, s = i % SLEN;
    ss_sh[hh * SLEN + s] = ssrc[(sbeg + s) * 4 + hh];
  }
  __syncthreads();

  const int tid = threadIdx.x;
  const int lane = tid & 63;
  const int h = tid >> 6;  // wave = head
  const int row = lane & 15;
  const int kg = lane >> 4;
  const int tRow = t0 + row;

  const float ce = ce_all[h];
  const float sd_t = sdst[tRow * 4 + h];
  const float ma_t = mean_attr[tRow];
  const float* arow = aggT + (size_t)tRow * NN;
  const float* ssh = ss_sh + h * SLEN;
  const int bloff = kg * 128 + row * 8;
  const __hip_bfloat16* bbase = hTsw + (size_t)(h * 8) * (NN * 16) + bloff;

  f32x4 acc[8];
#pragma unroll
  for (int f = 0; f < 8; ++f) acc[f] = (f32x4){0.f, 0.f, 0.f, 0.f};
  float dpart = 0.f;

  for (int s0 = sbeg; s0 < sbeg + SLEN; s0 += 32) {
    const int sk = s0 + kg * 8;
    f32x4 a0 = *(const f32x4*)(arow + sk);
    f32x4 a1 = *(const f32x4*)(arow + sk + 4);
    f32x4 sv0 = *(const f32x4*)(ssh + (sk - sbeg));
    f32x4 sv1 = *(const f32x4*)(ssh + (sk - sbeg) + 4);
    float av[8] = {a0.x, a0.y, a0.z, a0.w, a1.x, a1.y, a1.z, a1.w};
    float sv[8] = {sv0.x, sv0.y, sv0.z, sv0.w, sv1.x, sv1.y, sv1.z, sv1.w};
    short pb[8];
#pragma unroll
    for (int j = 0; j < 8; ++j) {
      const int s = sk + j;
      const float a = av[j];
      const bool diag = (s == tRow);
      const float ev = diag ? ma_t : a;
      const bool adj = diag || (a > 0.f);
      float l = sv[j] + sd_t + ev * ce;
      l = fmaxf(l, NEG_SLOPE * l);
      const float p = adj ? __expf(l) : 0.f;
      dpart += p;
      pb[j] = f2bf(p);
    }
    bf16x8 A = {pb[0], pb[1], pb[2], pb[3], pb[4], pb[5], pb[6], pb[7]};
    const __hip_bfloat16* bp = bbase + (size_t)s0 * 16;
#pragma unroll
    for (int f = 0; f < 8; ++f) {
      bf16x8 B = *(const bf16x8*)(bp + (size_t)f * (NN * 16));
      acc[f] = __builtin_amdgcn_mfma_f32_16x16x32_bf16(A, B, acc[f], 0, 0, 0);
    }
  }

  dpart += __shfl_xor(dpart, 16);
  dpart += __shfl_xor(dpart, 32);
  if (lane < 16) dden[((size_t)split * NN + tRow) * 4 + h] = dpart;

#pragma unroll
  for (int f = 0; f < 8; ++f) {
    const int col = h * 128 + f * 16 + row;
#pragma unroll
    for (int r = 0; r < 4; ++r) {
      const int trow = t0 + kg * 4 + r;
      num[((size_t)split * NN + trow) * 512 + col] = acc[f][r];
    }
  }
}

// ---------------------------------------------------------------------------
// Layer-2 fused attention (1 head): 4 waves 2Mx2N over 32 targets x 128 cols.
// ---------------------------------------------------------------------------
template <int SPLITS>
__global__ __launch_bounds__(256) void k_attn2(
    const float* __restrict__ aggT, const __hip_bfloat16* __restrict__ hTsw,
    const float* __restrict__ ssrc, const float* __restrict__ sdst,
    const float* __restrict__ mean_attr, const float* __restrict__ ce_all,
    float* __restrict__ num, float* __restrict__ dden) {
  constexpr int SLEN = NN / SPLITS;
  const int t0 = blockIdx.x * 32;
  const int split = blockIdx.y;
  const int sbeg = split * SLEN;
  const float ce = ce_all[4];

  __shared__ float ss_sh[SLEN];
  for (int i = threadIdx.x; i < SLEN; i += 256) ss_sh[i] = ssrc[sbeg + i];
  __syncthreads();

  const int tid = threadIdx.x;
  const int lane = tid & 63;
  const int w = tid >> 6;
  const int wm = w & 1;
  const int wn = w >> 1;
  const int m0 = t0 + wm * 16;
  const int row = lane & 15;
  const int kg = lane >> 4;
  const int tRow = m0 + row;

  const float sd_t = sdst[tRow];
  const float ma_t = mean_attr[tRow];
  const float* arow = aggT + (size_t)tRow * NN;
  const int bloff = kg * 128 + row * 8;
  const __hip_bfloat16* bbase = hTsw + (size_t)(wn * 4) * (NN * 16) + bloff;

  f32x4 acc[4];
#pragma unroll
  for (int f = 0; f < 4; ++f) acc[f] = (f32x4){0.f, 0.f, 0.f, 0.f};
  float dpart = 0.f;

  for (int s0 = sbeg; s0 < sbeg + SLEN; s0 += 32) {
    const int sk = s0 + kg * 8;
    f32x4 a0 = *(const f32x4*)(arow + sk);
    f32x4 a1 = *(const f32x4*)(arow + sk + 4);
    f32x4 sv0 = *(const f32x4*)(ss_sh + (sk - sbeg));
    f32x4 sv1 = *(const f32x4*)(ss_sh + (sk - sbeg) + 4);
    float av[8] = {a0.x, a0.y, a0.z, a0.w, a1.x, a1.y, a1.z, a1.w};
    float sv[8] = {sv0.x, sv0.y, sv0.z, sv0.w, sv1.x, sv1.y, sv1.z, sv1.w};
    short pb[8];
#pragma unroll
    for (int j = 0; j < 8; ++j) {
      const int s = sk + j;
      const float a = av[j];
      const bool diag = (s == tRow);
      const float ev = diag ? ma_t : a;
      const bool adj = diag || (a > 0.f);
      float l = sv[j] + sd_t + ev * ce;
      l = fmaxf(l, NEG_SLOPE * l);
      const float p = adj ? __expf(l) : 0.f;
      dpart += p;
      pb[j] = f2bf(p);
    }
    bf16x8 A = {pb[0], pb[1], pb[2], pb[3], pb[4], pb[5], pb[6], pb[7]};
    const __hip_bfloat16* bp = bbase + (size_t)s0 * 16;
#pragma unroll
    for (int f = 0; f < 4; ++f) {
      bf16x8 B = *(const bf16x8*)(bp + (size_t)f * (NN * 16));
      acc[f] = __builtin_amdgcn_mfma_f32_16x16x32_bf16(A, B, acc[f], 0, 0, 0);
    }
  }

  dpart += __shfl_xor(dpart, 16);
  dpart += __shfl_xor(dpart, 32);
  if (wn == 0 && lane < 16) dden[(size_t)split * NN + tRow] = dpart;

#pragma unroll
  for (int f = 0; f < 4; ++f) {
    const int col = wn * 64 + f * 16 + row;
#pragma unroll
    for (int r = 0; r < 4; ++r) {
      const int trow = m0 + kg * 4 + r;
      num[((size_t)split * NN + trow) * 128 + col] = acc[f][r];
    }
  }
}

// ---------------------------------------------------------------------------
// Combine split partials: layer1 -> ReLU -> bf16 feat1 ; layer2 -> fp32 feat2
// ---------------------------------------------------------------------------
template <int S>
__global__ __launch_bounds__(256) void k_combine1(const float* __restrict__ num,
                                                  const float* __restrict__ dd,
                                                  const float* __restrict__ bias,
                                                  __hip_bfloat16* __restrict__ outf) {
  const size_t TOT = (size_t)NN * 512;
  for (size_t e = (size_t)blockIdx.x * 256 + threadIdx.x; e < TOT;
       e += (size_t)gridDim.x * 256) {
    int t = (int)(e >> 9), j = (int)(e & 511);
    int h = j >> 7;
    float nsum = 0.f, dsum = 0.f;
#pragma unroll
    for (int p = 0; p < S; ++p) nsum += num[(size_t)p * TOT + e];
#pragma unroll
    for (int p = 0; p < S; ++p) dsum += dd[((size_t)p * NN + t) * 4 + h];
    float v = nsum / dsum + bias[j];
    outf[e] = __float2bfloat16(v > 0.f ? v : 0.f);
  }
}

template <int S>
__global__ __launch_bounds__(256) void k_combine2(const float* __restrict__ num,
                                                  const float* __restrict__ dd,
                                                  const float* __restrict__ bias,
                                                  float* __restrict__ outf) {
  const size_t TOT = (size_t)NN * 128;
  for (size_t e = (size_t)blockIdx.x * 256 + threadIdx.x; e < TOT;
       e += (size_t)gridDim.x * 256) {
    int t = (int)(e >> 7), c = (int)(e & 127);
    float nsum = 0.f, dsum = 0.f;
#pragma unroll
    for (int p = 0; p < S; ++p) nsum += num[(size_t)p * TOT + e];
#pragma unroll
    for (int p = 0; p < S; ++p) dsum += dd[(size_t)p * NN + t];
    outf[e] = nsum / dsum + bias[c];
  }
}

// ---------------------------------------------------------------------------
// Fused segment-mean-pool + fc + log_softmax. One block per group (8 blocks);
// each group's output row is independent.
// ---------------------------------------------------------------------------
__global__ __launch_bounds__(128) void k_poolhead(const float* __restrict__ feat,
                                                  const int* __restrict__ bidx,
                                                  const float* __restrict__ fcw,
                                                  const float* __restrict__ fcb,
                                                  float* __restrict__ out) {
  const int g = blockIdx.x;
  __shared__ int lo[2];
  __shared__ float psh[128];
  __shared__ float lsh[10];
  if (threadIdx.x == 0) { lo[0] = NN; lo[1] = NN; }
  __syncthreads();
  for (int n = threadIdx.x; n < NN; n += 128) {
    int b = bidx[n];
    int bprev = (n == 0) ? -1 : bidx[n - 1];
    if (b >= g && bprev < g) atomicMin(&lo[0], n);
    if (b >= g + 1 && bprev < g + 1) atomicMin(&lo[1], n);
  }
  __syncthreads();
  int s = lo[0], e = lo[1];
  float sum = 0.f;
  for (int n = s; n < e; ++n) sum += feat[(size_t)n * 128 + threadIdx.x];
  float cntf = (float)((e - s) > 1 ? (e - s) : 1);
  psh[threadIdx.x] = sum / cntf;
  __syncthreads();
  if (threadIdx.x < 10) {
    float v = fcb[threadIdx.x];
    for (int c = 0; c < 128; ++c) v += psh[c] * fcw[c * 10 + threadIdx.x];
    lsh[threadIdx.x] = v;
  }
  __syncthreads();
  if (threadIdx.x < 10) {
    float m = -1e30f;
    for (int i = 0; i < 10; ++i) m = fmaxf(m, lsh[i]);
    float den = 0.f;
    for (int i = 0; i < 10; ++i) den += expf(lsh[i] - m);
    out[g * 10 + threadIdx.x] = lsh[threadIdx.x] - m - logf(den);
  }
}

extern "C" void kernel_launch(void* const* d_in, const int* in_sizes, int n_in,
                              void* d_out, int out_size, void* d_ws,
                              size_t ws_size, hipStream_t stream) {
  (void)in_sizes; (void)n_in; (void)out_size; (void)ws_size;
  const float* x      = (const float*)d_in[0];
  const float* attn   = (const float*)d_in[1];
  const int*   bidx   = (const int*)d_in[2];
  const float* conv_w = (const float*)d_in[3];
  const float* conv_b = (const float*)d_in[4];
  const float* W1     = (const float*)d_in[5];
  const float* asrc1  = (const float*)d_in[6];
  const float* adst1  = (const float*)d_in[7];
  const float* aedge1 = (const float*)d_in[8];
  const float* We1    = (const float*)d_in[9];
  const float* b1     = (const float*)d_in[10];
  const float* W2     = (const float*)d_in[11];
  const float* asrc2  = (const float*)d_in[12];
  const float* adst2  = (const float*)d_in[13];
  const float* aedge2 = (const float*)d_in[14];
  const float* We2    = (const float*)d_in[15];
  const float* b2     = (const float*)d_in[16];
  const float* fcw    = (const float*)d_in[17];
  const float* fcb    = (const float*)d_in[18];

  float* ws = (float*)d_ws;
  float* aggT  = ws;                        // 4,194,304
  float* num1  = aggT + 4194304;            // 2,097,152 (2 x 2048 x 512)
  float* num2  = num1 + 2097152;            // 1,048,576 (4 x 2048 x 128)
  float* feat2 = num2 + 1048576;            //   262,144
  float* stats = feat2 + 262144;            //    24,576 (contiguous, memset)
  float* colsum = stats;                    //     2,048
  float* colcnt = colsum + 2048;            //     2,048
  float* ssrc1 = colcnt + 2048;             //     8,192
  float* sdst1 = ssrc1 + 8192;              //     8,192
  float* ssrc2 = sdst1 + 8192;              //     2,048
  float* sdst2 = ssrc2 + 2048;              //     2,048
  float* mean_attr = stats + 24576;         //     2,048
  float* ce    = mean_attr + 2048;          //        64
  float* d1    = ce + 64;                   //    16,384 (2 x 2048 x 4)
  float* d2    = d1 + 16384;                //     8,192 (4 x 2048)
  float* bfreg = d2 + 8192;
  __hip_bfloat16* xb     = (__hip_bfloat16*)bfreg;             // 262,144 el
  __hip_bfloat16* w1t    = (__hip_bfloat16*)(bfreg + 131072);  //  65,536 el
  __hip_bfloat16* w2t    = (__hip_bfloat16*)(bfreg + 163840);  //  65,536 el
  __hip_bfloat16* hTsw1  = (__hip_bfloat16*)(bfreg + 196608);  // 1,048,576 el
  __hip_bfloat16* hTsw2  = (__hip_bfloat16*)(bfreg + 720896);  //   262,144 el
  __hip_bfloat16* feat1b = (__hip_bfloat16*)(bfreg + 851968);  // 1,048,576 el

  hipMemsetAsync(stats, 0, 24576 * sizeof(float), stream);
  k_agg<<<dim3(2, 128), 256, 0, stream>>>(attn, conv_w, conv_b, aggT, colsum,
                                          colcnt);
  k_setup<<<329, 256, 0, stream>>>(x, W1, W2, aedge1, We1, aedge2, We2, colsum,
                                   colcnt, xb, w1t, w2t, mean_attr, ce);
  k_gemm_fused<4, 4><<<dim3(128, 8), 64, 0, stream>>>(xb, w1t, hTsw1, asrc1,
                                                      adst1, ssrc1, sdst1);
  k_attn1<2><<<dim3(128, 2), 256, 0, stream>>>(aggT, hTsw1, ssrc1, sdst1,
                                               mean_attr, ce, num1, d1);
  k_combine1<2><<<1024, 256, 0, stream>>>(num1, d1, b1, feat1b);
  k_gemm_fused<16, 1><<<dim3(128, 2), 64, 0, stream>>>(feat1b, w2t, hTsw2,
                                                       asrc2, adst2, ssrc2,
                                                       sdst2);
  k_attn2<4><<<dim3(64, 4), 256, 0, stream>>>(aggT, hTsw2, ssrc2, sdst2,
                                              mean_attr, ce, num2, d2);
  k_combine2<4><<<512, 256, 0, stream>>>(num2, d2, b2, feat2);
  k_poolhead<<<8, 128, 0, stream>>>(feat2, bidx, fcw, fcb, (float*)d_out);
}

// Round 5
// 223.211 us; speedup vs baseline: 1.1760x; 1.1760x over previous
//
#include <hip/hip_runtime.h>
#include <hip/hip_bf16.h>
#include <math.h>

#define NN 2048
#define NEG_SLOPE 0.2f

typedef __attribute__((ext_vector_type(8))) short bf16x8;
typedef __attribute__((ext_vector_type(4))) float f32x4;

static __device__ inline short f2bf(float x) {
  union { float f; unsigned u; } v;
  v.f = x;
  unsigned r = v.u + 0x7fffu + ((v.u >> 16) & 1u);  // RNE
  return (short)(r >> 16);
}

// ---------------------------------------------------------------------------
// Zero the atomic-accumulator region (replaces pathological hipMemsetAsync).
// ---------------------------------------------------------------------------
__global__ __launch_bounds__(256) void k_zero(float* __restrict__ p, int n4) {
  const int i = (blockIdx.x * 256 + threadIdx.x) * 4;
  if (i < n4 * 4) *(f32x4*)(p + i) = (f32x4){0.f, 0.f, 0.f, 0.f};
}

// ---------------------------------------------------------------------------
// K1: agg[s,t] = sum_c conv_w[c]*attn[c,s,t] + conv_b ; store TRANSPOSED
//     aggT[t][s], plus atomic per-target column stats (sum/cnt of masked).
// Block: 1024 t (float4/lane) x 16 s. Grid (2,128).
// ---------------------------------------------------------------------------
__global__ __launch_bounds__(256) void k_agg(const float* __restrict__ attn,
                                             const float* __restrict__ conv_w,
                                             const float* __restrict__ conv_b,
                                             float* __restrict__ aggT,
                                             float* __restrict__ colsum,
                                             float* __restrict__ colcnt) {
  const int t = blockIdx.x * 1024 + threadIdx.x * 4;
  const int s0 = blockIdx.y * 16;
  float w[12];
#pragma unroll
  for (int c = 0; c < 12; ++c) w[c] = conv_w[c];
  const float cb = conv_b[0];
  f32x4 acc[16];
#pragma unroll
  for (int s = 0; s < 16; ++s) acc[s] = (f32x4){cb, cb, cb, cb};
  for (int c = 0; c < 12; ++c) {
    const float* base = attn + (size_t)c * NN * NN + (size_t)s0 * NN + t;
#pragma unroll
    for (int s = 0; s < 16; ++s) {
      f32x4 v = *(const f32x4*)(base + (size_t)s * NN);
      acc[s] += w[c] * v;
    }
  }
  // write aggT rows
#pragma unroll
  for (int j = 0; j < 4; ++j) {
    float* orow = aggT + (size_t)(t + j) * NN + s0;
#pragma unroll
    for (int s = 0; s < 16; ++s) orow[s] = acc[s][j];
  }
  // stats: per target t+j over these 16 sources
#pragma unroll
  for (int j = 0; j < 4; ++j) {
    float psum = 0.f;
    float pcnt = 0.f;
#pragma unroll
    for (int s = 0; s < 16; ++s) {
      float a = acc[s][j];
      bool m = (a > 0.f) && (s0 + s != t + j);
      psum += m ? a : 0.f;
      pcnt += m ? 1.f : 0.f;
    }
    atomicAdd(colsum + t + j, psum);
    atomicAdd(colcnt + t + j, pcnt);
  }
}

// ---------------------------------------------------------------------------
// Setup kernel (block ranges): xb (0-255), w1t (256-287), w2t (288-319),
// mean_attr (320-327), ce (328).
// ---------------------------------------------------------------------------
__global__ __launch_bounds__(256) void k_setup(
    const float* __restrict__ x, const float* __restrict__ W1,
    const float* __restrict__ W2, const float* __restrict__ ae1,
    const float* __restrict__ We1, const float* __restrict__ ae2,
    const float* __restrict__ We2, const float* __restrict__ colsum,
    const float* __restrict__ colcnt, __hip_bfloat16* __restrict__ xb,
    __hip_bfloat16* __restrict__ w1t, __hip_bfloat16* __restrict__ w2t,
    float* __restrict__ mean_attr, float* __restrict__ ce) {
  const int b = blockIdx.x;
  const int tid = threadIdx.x;
  if (b < 256) {
    const int i = (b * 256 + tid) * 4;
    float4 v = *(const float4*)(x + i);
    short4 o;
    o.x = f2bf(v.x); o.y = f2bf(v.y); o.z = f2bf(v.z); o.w = f2bf(v.w);
    *(short4*)((short*)xb + i) = o;
  } else if (b < 288) {
#pragma unroll
    for (int k = 0; k < 8; ++k) {
      int o = (b - 256) * 2048 + k * 256 + tid;
      int c = o >> 7, r = o & 127;
      ((short*)w1t)[o] = f2bf(W1[r * 512 + c]);
    }
  } else if (b < 320) {
#pragma unroll
    for (int k = 0; k < 8; ++k) {
      int o = (b - 288) * 2048 + k * 256 + tid;
      int c = o >> 9, r = o & 511;
      ((short*)w2t)[o] = f2bf(W2[r * 128 + c]);
    }
  } else if (b < 328) {
    int t = (b - 320) * 256 + tid;
    float c = colcnt[t];
    mean_attr[t] = colsum[t] / fmaxf(c, 1.f);
  } else {
    const int lane = tid & 63;
    const int wv = tid >> 6;
    float p = ae1[wv * 128 + lane] * We1[wv * 128 + lane] +
              ae1[wv * 128 + 64 + lane] * We1[wv * 128 + 64 + lane];
    for (int off = 32; off; off >>= 1) p += __shfl_down(p, off);
    if (lane == 0) ce[wv] = p;
    float q = ae2[lane] * We2[lane] + ae2[64 + lane] * We2[64 + lane];
    for (int off = 32; off; off >>= 1) q += __shfl_down(q, off);
    if (tid == 0) ce[4] = q;
  }
}

// ---------------------------------------------------------------------------
// MFMA GEMM, 1 wave/block: out tile 16 rows x 64 cols. Writes ONLY the
// swizzled bf16 layout hTsw[cb][s/8][16cr][8s] (cb = 16-col block), and fused
// s_src/s_dst partial dots via atomicAdd (buffers pre-zeroed).
// ---------------------------------------------------------------------------
template <int KSTEPS, int NH>
__global__ __launch_bounds__(64) void k_gemm_fused(
    const __hip_bfloat16* __restrict__ A, const __hip_bfloat16* __restrict__ BT,
    __hip_bfloat16* __restrict__ hTsw, const float* __restrict__ asrc,
    const float* __restrict__ adst, float* __restrict__ ssrc,
    float* __restrict__ sdst) {
  constexpr int K = KSTEPS * 32;
  const int m0 = blockIdx.x * 16;
  const int n0 = blockIdx.y * 64;
  const int lane = threadIdx.x;
  const int row = lane & 15;
  const int kg = lane >> 4;
  const __hip_bfloat16* arow = A + (size_t)(m0 + row) * K + kg * 8;
  f32x4 acc[4];
#pragma unroll
  for (int f = 0; f < 4; ++f) acc[f] = (f32x4){0.f, 0.f, 0.f, 0.f};
#pragma unroll
  for (int ks = 0; ks < KSTEPS; ++ks) {
    bf16x8 Af = *(const bf16x8*)(arow + ks * 32);
#pragma unroll
    for (int f = 0; f < 4; ++f) {
      bf16x8 Bf = *(const bf16x8*)(BT + (size_t)(n0 + f * 16 + row) * K +
                                   kg * 8 + ks * 32);
      acc[f] = __builtin_amdgcn_mfma_f32_16x16x32_bf16(Af, Bf, acc[f], 0, 0, 0);
    }
  }
  // fused s_src/s_dst partials
  const int h = (NH == 1) ? 0 : (n0 >> 7);
  float as[4], ad[4];
#pragma unroll
  for (int f = 0; f < 4; ++f) {
    int ch = (n0 + f * 16 + row) & 127;
    as[f] = asrc[h * 128 + ch];
    ad[f] = adst[h * 128 + ch];
  }
  float ps[4] = {0.f, 0.f, 0.f, 0.f}, pd[4] = {0.f, 0.f, 0.f, 0.f};
#pragma unroll
  for (int f = 0; f < 4; ++f)
#pragma unroll
    for (int r = 0; r < 4; ++r) {
      ps[r] += acc[f][r] * as[f];
      pd[r] += acc[f][r] * ad[f];
    }
#pragma unroll
  for (int m = 1; m < 16; m <<= 1) {
#pragma unroll
    for (int r = 0; r < 4; ++r) {
      ps[r] += __shfl_xor(ps[r], m);
      pd[r] += __shfl_xor(pd[r], m);
    }
  }
  if (row == 0) {
#pragma unroll
    for (int r = 0; r < 4; ++r) {
      int node = m0 + kg * 4 + r;
      atomicAdd(&ssrc[node * NH + h], ps[r]);
      atomicAdd(&sdst[node * NH + h], pd[r]);
    }
  }
  // swizzled bf16 write: elem addr = cb*NN*16 + sblk*128 + cr*8 + (s&7)
#pragma unroll
  for (int f = 0; f < 4; ++f) {
    const int cbi = blockIdx.y * 4 + f;
    short4 ct;
    ct.x = f2bf(acc[f][0]); ct.y = f2bf(acc[f][1]);
    ct.z = f2bf(acc[f][2]); ct.w = f2bf(acc[f][3]);
    size_t a4 = (size_t)cbi * (NN * 16) +
                (size_t)(((m0 >> 3) + (kg >> 1)) * 128 + row * 8 + (kg & 1) * 4);
    *(short4*)((short*)hTsw + a4) = ct;
  }
}

// ---------------------------------------------------------------------------
// Layer-1 fused attention: 4 waves = 4 heads sharing 16 target rows.
// B-frags from swizzled hTsw: one contiguous 1KB block per wave per load.
// ---------------------------------------------------------------------------
template <int SPLITS>
__global__ __launch_bounds__(256) void k_attn1(
    const float* __restrict__ aggT, const __hip_bfloat16* __restrict__ hTsw,
    const float* __restrict__ ssrc, const float* __restrict__ sdst,
    const float* __restrict__ mean_attr, const float* __restrict__ ce_all,
    float* __restrict__ num, float* __restrict__ dden) {
  constexpr int SLEN = NN / SPLITS;
  const int t0 = blockIdx.x * 16;
  const int split = blockIdx.y;
  const int sbeg = split * SLEN;

  __shared__ float ss_sh[4 * SLEN];
  for (int i = threadIdx.x; i < 4 * SLEN; i += 256) {
    int hh = i / SLEN, s = i % SLEN;
    ss_sh[hh * SLEN + s] = ssrc[(sbeg + s) * 4 + hh];
  }
  __syncthreads();

  const int tid = threadIdx.x;
  const int lane = tid & 63;
  const int h = tid >> 6;  // wave = head
  const int row = lane & 15;
  const int kg = lane >> 4;
  const int tRow = t0 + row;

  const float ce = ce_all[h];
  const float sd_t = sdst[tRow * 4 + h];
  const float ma_t = mean_attr[tRow];
  const float* arow = aggT + (size_t)tRow * NN;
  const float* ssh = ss_sh + h * SLEN;
  const int bloff = kg * 128 + row * 8;
  const __hip_bfloat16* bbase = hTsw + (size_t)(h * 8) * (NN * 16) + bloff;

  f32x4 acc[8];
#pragma unroll
  for (int f = 0; f < 8; ++f) acc[f] = (f32x4){0.f, 0.f, 0.f, 0.f};
  float dpart = 0.f;

  for (int s0 = sbeg; s0 < sbeg + SLEN; s0 += 32) {
    const int sk = s0 + kg * 8;
    f32x4 a0 = *(const f32x4*)(arow + sk);
    f32x4 a1 = *(const f32x4*)(arow + sk + 4);
    f32x4 sv0 = *(const f32x4*)(ssh + (sk - sbeg));
    f32x4 sv1 = *(const f32x4*)(ssh + (sk - sbeg) + 4);
    float av[8] = {a0.x, a0.y, a0.z, a0.w, a1.x, a1.y, a1.z, a1.w};
    float sv[8] = {sv0.x, sv0.y, sv0.z, sv0.w, sv1.x, sv1.y, sv1.z, sv1.w};
    short pb[8];
#pragma unroll
    for (int j = 0; j < 8; ++j) {
      const int s = sk + j;
      const float a = av[j];
      const bool diag = (s == tRow);
      const float ev = diag ? ma_t : a;
      const bool adj = diag || (a > 0.f);
      float l = sv[j] + sd_t + ev * ce;
      l = fmaxf(l, NEG_SLOPE * l);
      const float p = adj ? __expf(l) : 0.f;
      dpart += p;
      pb[j] = f2bf(p);
    }
    bf16x8 A = {pb[0], pb[1], pb[2], pb[3], pb[4], pb[5], pb[6], pb[7]};
    const __hip_bfloat16* bp = bbase + (size_t)s0 * 16;
#pragma unroll
    for (int f = 0; f < 8; ++f) {
      bf16x8 B = *(const bf16x8*)(bp + (size_t)f * (NN * 16));
      acc[f] = __builtin_amdgcn_mfma_f32_16x16x32_bf16(A, B, acc[f], 0, 0, 0);
    }
  }

  dpart += __shfl_xor(dpart, 16);
  dpart += __shfl_xor(dpart, 32);
  if (lane < 16) dden[((size_t)split * NN + tRow) * 4 + h] = dpart;

#pragma unroll
  for (int f = 0; f < 8; ++f) {
    const int col = h * 128 + f * 16 + row;
#pragma unroll
    for (int r = 0; r < 4; ++r) {
      const int trow = t0 + kg * 4 + r;
      num[((size_t)split * NN + trow) * 512 + col] = acc[f][r];
    }
  }
}

// ---------------------------------------------------------------------------
// Layer-2 fused attention (1 head): 4 waves 2Mx2N over 32 targets x 128 cols.
// ---------------------------------------------------------------------------
template <int SPLITS>
__global__ __launch_bounds__(256) void k_attn2(
    const float* __restrict__ aggT, const __hip_bfloat16* __restrict__ hTsw,
    const float* __restrict__ ssrc, const float* __restrict__ sdst,
    const float* __restrict__ mean_attr, const float* __restrict__ ce_all,
    float* __restrict__ num, float* __restrict__ dden) {
  constexpr int SLEN = NN / SPLITS;
  const int t0 = blockIdx.x * 32;
  const int split = blockIdx.y;
  const int sbeg = split * SLEN;
  const float ce = ce_all[4];

  __shared__ float ss_sh[SLEN];
  for (int i = threadIdx.x; i < SLEN; i += 256) ss_sh[i] = ssrc[sbeg + i];
  __syncthreads();

  const int tid = threadIdx.x;
  const int lane = tid & 63;
  const int w = tid >> 6;
  const int wm = w & 1;
  const int wn = w >> 1;
  const int m0 = t0 + wm * 16;
  const int row = lane & 15;
  const int kg = lane >> 4;
  const int tRow = m0 + row;

  const float sd_t = sdst[tRow];
  const float ma_t = mean_attr[tRow];
  const float* arow = aggT + (size_t)tRow * NN;
  const int bloff = kg * 128 + row * 8;
  const __hip_bfloat16* bbase = hTsw + (size_t)(wn * 4) * (NN * 16) + bloff;

  f32x4 acc[4];
#pragma unroll
  for (int f = 0; f < 4; ++f) acc[f] = (f32x4){0.f, 0.f, 0.f, 0.f};
  float dpart = 0.f;

  for (int s0 = sbeg; s0 < sbeg + SLEN; s0 += 32) {
    const int sk = s0 + kg * 8;
    f32x4 a0 = *(const f32x4*)(arow + sk);
    f32x4 a1 = *(const f32x4*)(arow + sk + 4);
    f32x4 sv0 = *(const f32x4*)(ss_sh + (sk - sbeg));
    f32x4 sv1 = *(const f32x4*)(ss_sh + (sk - sbeg) + 4);
    float av[8] = {a0.x, a0.y, a0.z, a0.w, a1.x, a1.y, a1.z, a1.w};
    float sv[8] = {sv0.x, sv0.y, sv0.z, sv0.w, sv1.x, sv1.y, sv1.z, sv1.w};
    short pb[8];
#pragma unroll
    for (int j = 0; j < 8; ++j) {
      const int s = sk + j;
      const float a = av[j];
      const bool diag = (s == tRow);
      const float ev = diag ? ma_t : a;
      const bool adj = diag || (a > 0.f);
      float l = sv[j] + sd_t + ev * ce;
      l = fmaxf(l, NEG_SLOPE * l);
      const float p = adj ? __expf(l) : 0.f;
      dpart += p;
      pb[j] = f2bf(p);
    }
    bf16x8 A = {pb[0], pb[1], pb[2], pb[3], pb[4], pb[5], pb[6], pb[7]};
    const __hip_bfloat16* bp = bbase + (size_t)s0 * 16;
#pragma unroll
    for (int f = 0; f < 4; ++f) {
      bf16x8 B = *(const bf16x8*)(bp + (size_t)f * (NN * 16));
      acc[f] = __builtin_amdgcn_mfma_f32_16x16x32_bf16(A, B, acc[f], 0, 0, 0);
    }
  }

  dpart += __shfl_xor(dpart, 16);
  dpart += __shfl_xor(dpart, 32);
  if (wn == 0 && lane < 16) dden[(size_t)split * NN + tRow] = dpart;

#pragma unroll
  for (int f = 0; f < 4; ++f) {
    const int col = wn * 64 + f * 16 + row;
#pragma unroll
    for (int r = 0; r < 4; ++r) {
      const int trow = m0 + kg * 4 + r;
      num[((size_t)split * NN + trow) * 128 + col] = acc[f][r];
    }
  }
}

// ---------------------------------------------------------------------------
// Combine split partials: layer1 -> ReLU -> bf16 feat1 ; layer2 -> fp32 feat2
// ---------------------------------------------------------------------------
template <int S>
__global__ __launch_bounds__(256) void k_combine1(const float* __restrict__ num,
                                                  const float* __restrict__ dd,
                                                  const float* __restrict__ bias,
                                                  __hip_bfloat16* __restrict__ outf) {
  const size_t TOT = (size_t)NN * 512;
  for (size_t e = (size_t)blockIdx.x * 256 + threadIdx.x; e < TOT;
       e += (size_t)gridDim.x * 256) {
    int t = (int)(e >> 9), j = (int)(e & 511);
    int h = j >> 7;
    float nsum = 0.f, dsum = 0.f;
#pragma unroll
    for (int p = 0; p < S; ++p) nsum += num[(size_t)p * TOT + e];
#pragma unroll
    for (int p = 0; p < S; ++p) dsum += dd[((size_t)p * NN + t) * 4 + h];
    float v = nsum / dsum + bias[j];
    outf[e] = __float2bfloat16(v > 0.f ? v : 0.f);
  }
}

template <int S>
__global__ __launch_bounds__(256) void k_combine2(const float* __restrict__ num,
                                                  const float* __restrict__ dd,
                                                  const float* __restrict__ bias,
                                                  float* __restrict__ outf) {
  const size_t TOT = (size_t)NN * 128;
  for (size_t e = (size_t)blockIdx.x * 256 + threadIdx.x; e < TOT;
       e += (size_t)gridDim.x * 256) {
    int t = (int)(e >> 7), c = (int)(e & 127);
    float nsum = 0.f, dsum = 0.f;
#pragma unroll
    for (int p = 0; p < S; ++p) nsum += num[(size_t)p * TOT + e];
#pragma unroll
    for (int p = 0; p < S; ++p) dsum += dd[(size_t)p * NN + t];
    outf[e] = nsum / dsum + bias[c];
  }
}

// ---------------------------------------------------------------------------
// Fused segment-mean-pool + fc + log_softmax. One block per group (8 blocks);
// each group's output row is independent.
// ---------------------------------------------------------------------------
__global__ __launch_bounds__(128) void k_poolhead(const float* __restrict__ feat,
                                                  const int* __restrict__ bidx,
                                                  const float* __restrict__ fcw,
                                                  const float* __restrict__ fcb,
                                                  float* __restrict__ out) {
  const int g = blockIdx.x;
  __shared__ int lo[2];
  __shared__ float psh[128];
  __shared__ float lsh[10];
  if (threadIdx.x == 0) { lo[0] = NN; lo[1] = NN; }
  __syncthreads();
  for (int n = threadIdx.x; n < NN; n += 128) {
    int b = bidx[n];
    int bprev = (n == 0) ? -1 : bidx[n - 1];
    if (b >= g && bprev < g) atomicMin(&lo[0], n);
    if (b >= g + 1 && bprev < g + 1) atomicMin(&lo[1], n);
  }
  __syncthreads();
  int s = lo[0], e = lo[1];
  float sum = 0.f;
  for (int n = s; n < e; ++n) sum += feat[(size_t)n * 128 + threadIdx.x];
  float cntf = (float)((e - s) > 1 ? (e - s) : 1);
  psh[threadIdx.x] = sum / cntf;
  __syncthreads();
  if (threadIdx.x < 10) {
    float v = fcb[threadIdx.x];
    for (int c = 0; c < 128; ++c) v += psh[c] * fcw[c * 10 + threadIdx.x];
    lsh[threadIdx.x] = v;
  }
  __syncthreads();
  if (threadIdx.x < 10) {
    float m = -1e30f;
    for (int i = 0; i < 10; ++i) m = fmaxf(m, lsh[i]);
    float den = 0.f;
    for (int i = 0; i < 10; ++i) den += expf(lsh[i] - m);
    out[g * 10 + threadIdx.x] = lsh[threadIdx.x] - m - logf(den);
  }
}

extern "C" void kernel_launch(void* const* d_in, const int* in_sizes, int n_in,
                              void* d_out, int out_size, void* d_ws,
                              size_t ws_size, hipStream_t stream) {
  (void)in_sizes; (void)n_in; (void)out_size; (void)ws_size;
  const float* x      = (const float*)d_in[0];
  const float* attn   = (const float*)d_in[1];
  const int*   bidx   = (const int*)d_in[2];
  const float* conv_w = (const float*)d_in[3];
  const float* conv_b = (const float*)d_in[4];
  const float* W1     = (const float*)d_in[5];
  const float* asrc1  = (const float*)d_in[6];
  const float* adst1  = (const float*)d_in[7];
  const float* aedge1 = (const float*)d_in[8];
  const float* We1    = (const float*)d_in[9];
  const float* b1     = (const float*)d_in[10];
  const float* W2     = (const float*)d_in[11];
  const float* asrc2  = (const float*)d_in[12];
  const float* adst2  = (const float*)d_in[13];
  const float* aedge2 = (const float*)d_in[14];
  const float* We2    = (const float*)d_in[15];
  const float* b2     = (const float*)d_in[16];
  const float* fcw    = (const float*)d_in[17];
  const float* fcb    = (const float*)d_in[18];

  float* ws = (float*)d_ws;
  float* aggT  = ws;                        // 4,194,304
  float* num1  = aggT + 4194304;            // 4,194,304 (4 x 2048 x 512)
  float* num2  = num1 + 4194304;            // 2,097,152 (8 x 2048 x 128)
  float* feat2 = num2 + 2097152;            //   262,144
  float* stats = feat2 + 262144;            //    24,576 (contiguous, zeroed)
  float* colsum = stats;                    //     2,048
  float* colcnt = colsum + 2048;            //     2,048
  float* ssrc1 = colcnt + 2048;             //     8,192
  float* sdst1 = ssrc1 + 8192;              //     8,192
  float* ssrc2 = sdst1 + 8192;              //     2,048
  float* sdst2 = ssrc2 + 2048;              //     2,048
  float* mean_attr = stats + 24576;         //     2,048
  float* ce    = mean_attr + 2048;          //        64
  float* d1    = ce + 64;                   //    32,768 (4 x 2048 x 4)
  float* d2    = d1 + 32768;                //    16,384 (8 x 2048)
  float* bfreg = d2 + 16384;
  __hip_bfloat16* xb     = (__hip_bfloat16*)bfreg;             // 262,144 el
  __hip_bfloat16* w1t    = (__hip_bfloat16*)(bfreg + 131072);  //  65,536 el
  __hip_bfloat16* w2t    = (__hip_bfloat16*)(bfreg + 163840);  //  65,536 el
  __hip_bfloat16* hTsw1  = (__hip_bfloat16*)(bfreg + 196608);  // 1,048,576 el
  __hip_bfloat16* hTsw2  = (__hip_bfloat16*)(bfreg + 720896);  //   262,144 el
  __hip_bfloat16* feat1b = (__hip_bfloat16*)(bfreg + 851968);  // 1,048,576 el

  k_zero<<<24, 256, 0, stream>>>(stats, 6144);
  k_agg<<<dim3(2, 128), 256, 0, stream>>>(attn, conv_w, conv_b, aggT, colsum,
                                          colcnt);
  k_setup<<<329, 256, 0, stream>>>(x, W1, W2, aedge1, We1, aedge2, We2, colsum,
                                   colcnt, xb, w1t, w2t, mean_attr, ce);
  k_gemm_fused<4, 4><<<dim3(128, 8), 64, 0, stream>>>(xb, w1t, hTsw1, asrc1,
                                                      adst1, ssrc1, sdst1);
  k_attn1<4><<<dim3(128, 4), 256, 0, stream>>>(aggT, hTsw1, ssrc1, sdst1,
                                               mean_attr, ce, num1, d1);
  k_combine1<4><<<1024, 256, 0, stream>>>(num1, d1, b1, feat1b);
  k_gemm_fused<16, 1><<<dim3(128, 2), 64, 0, stream>>>(feat1b, w2t, hTsw2,
                                                       asrc2, adst2, ssrc2,
                                                       sdst2);
  k_attn2<8><<<dim3(64, 8), 256, 0, stream>>>(aggT, hTsw2, ssrc2, sdst2,
                                              mean_attr, ce, num2, d2);
  k_combine2<8><<<512, 256, 0, stream>>>(num2, d2, b2, feat2);
  k_poolhead<<<8, 128, 0, stream>>>(feat2, bidx, fcw, fcb, (float*)d_out);
}